// Round 8
// baseline (303.160 us; speedup 1.0000x reference)
//
#include <hip/hip_runtime.h>
#include <math.h>

// Problem constants (SpiralDeblock)
#define B      16
#define N_IN   7000
#define N_OUT  28000
#define C      64          // C_IN == C_OUT == 64
#define S      9
#define NNZ    (3 * N_OUT) // 84000
#define F      (S * C)     // 576
#define KB     (F / 32)    // 18 k-blocks of 32 for mfma 16x16x32

typedef short bf16x8 __attribute__((ext_vector_type(8)));  // 8 bf16 = 4 VGPRs
typedef float f32x4  __attribute__((ext_vector_type(4)));

// fp32 -> bf16 round-to-nearest-even (bit pattern as ushort)
static __device__ __forceinline__ unsigned short f2bf(float f) {
    unsigned u = __float_as_uint(f);
    u += 0x7fffu + ((u >> 16) & 1u);
    return (unsigned short)(u >> 16);
}
static __device__ __forceinline__ float bf2f(unsigned short s) {
    return __uint_as_float((unsigned)s << 16);
}

// ---------------------------------------------------------------------------
// Fused prep (R8: 3 launches -> 1): blocks [0,3500) convert x->bf16;
// blocks [3500,3829) histogram rows; blocks [3829,3847) pack W.
// All three are independent of each other.
// ---------------------------------------------------------------------------
#define XBF_BLOCKS  3500
#define HIST_BLOCKS 329   // ceil(84000/256)
#define PACK_BLOCKS 18

__global__ void prep_kernel(const float* __restrict__ x, unsigned short* __restrict__ xb,
                            const float* __restrict__ w, unsigned short* __restrict__ pw,
                            const int*   __restrict__ row, int* __restrict__ cnt) {
    const int blk = blockIdx.x;
    const int tid = threadIdx.x;
    if (blk < XBF_BLOCKS) {
        const size_t i = ((size_t)blk * 256 + tid) * 8;
        const float4 a = *(const float4*)(x + i);
        const float4 c = *(const float4*)(x + i + 4);
        ushort4 o0, o1;
        o0.x = f2bf(a.x); o0.y = f2bf(a.y); o0.z = f2bf(a.z); o0.w = f2bf(a.w);
        o1.x = f2bf(c.x); o1.y = f2bf(c.y); o1.z = f2bf(c.z); o1.w = f2bf(c.w);
        *(ushort4*)(xb + i)     = o0;
        *(ushort4*)(xb + i + 4) = o1;
    } else if (blk < XBF_BLOCKS + HIST_BLOCKS) {
        const int i = (blk - XBF_BLOCKS) * 256 + tid;
        if (i < NNZ) atomicAdd(&cnt[row[i]], 1);
    } else {
        const int kb   = blk - (XBF_BLOCKS + HIST_BLOCKS);   // 0..17
        const int nt   = tid >> 6;
        const int lane = tid & 63;
        const int lm   = lane & 15;
        const int quad = lane >> 4;
        unsigned short v[8];
        #pragma unroll
        for (int j = 0; j < 8; ++j) {
            const int k = kb * 32 + quad * 8 + j;
            const int n = nt * 16 + lm;
            v[j] = f2bf(w[(size_t)k * C + n]);
        }
        unsigned short* dst = pw + ((size_t)(kb * 4 + nt) * 64 + lane) * 8;
        #pragma unroll
        for (int j = 0; j < 8; ++j) dst[j] = v[j];
    }
}

// ---------------------------------------------------------------------------
// Scan (R8 rewrite): coalesced chunked scan. Old version had each thread
// load/store 28 ints at stride 112 B from ONE CU (~56K uncoalesced line
// requests). Now: 28 chunks of 1024, inclusive wave-scan via __shfl_up
// (no barriers), cross-wave prefix via 16-entry LDS, 2 barriers/chunk.
// ---------------------------------------------------------------------------
__global__ void scan_kernel(const int* __restrict__ cnt,
                            int* __restrict__ offs, int* __restrict__ cursor) {
    __shared__ int wsum[16];
    __shared__ int carry;
    const int t = threadIdx.x, lane = t & 63, wid = t >> 6;
    if (t == 0) carry = 0;
    __syncthreads();
    int lastTot = 0;
    #pragma unroll 1
    for (int chunk = 0; chunk < 28; ++chunk) {     // 28*1024 = 28672 >= 28000
        const int idx = chunk * 1024 + t;
        const int v = (idx < N_OUT) ? cnt[idx] : 0;
        const int cin = carry;                      // read BEFORE b1
        int sc = v;                                 // inclusive wave scan
        #pragma unroll
        for (int d = 1; d < 64; d <<= 1) {
            int u = __shfl_up(sc, d, 64);
            if (lane >= d) sc += u;
        }
        if (lane == 63) wsum[wid] = sc;
        __syncthreads();                            // b1: wsum visible
        int wexcl = 0;
        #pragma unroll
        for (int wj = 0; wj < 15; ++wj)
            wexcl += (wj < wid) ? wsum[wj] : 0;
        const int excl = cin + wexcl + sc - v;
        if (idx < N_OUT) { offs[idx] = excl; cursor[idx] = excl; }
        if (t == 1023) { lastTot = cin + wexcl + sc; carry = lastTot; }
        __syncthreads();                            // b2: carry update visible
    }
    if (t == 1023) offs[N_OUT] = lastTot;
}

__global__ void place_kernel(const int* __restrict__ row, const int* __restrict__ col,
                             const float* __restrict__ values,
                             int* __restrict__ cursor,
                             int* __restrict__ ecol, float* __restrict__ eval) {
    int i = blockIdx.x * 256 + threadIdx.x;
    if (i < NNZ) {
        int pos = atomicAdd(&cursor[row[i]], 1);
        ecol[pos] = col[i];
        eval[pos] = values[i];
    }
}

// ---------------------------------------------------------------------------
// Pooling from bf16 x, XCD-pinned by batch-pair (bg = blockIdx&7 owns
// batches {bg, bg+8}; xbf working set 1.79 MB/XCD, L2-resident).
// Wave: 2 rows x 2 batches x 16 sl; per edge one ushort4 (8 B)/lane =
// 128 B contiguous per (row,batch). 4-edge batching breaks the dependent
// ecol->x chain. Writes: [g][r][bp][c]; full 128 B line per (g,r,bp);
// nontemporal so the 57 MB write stream doesn't evict the pinned x slab.
// ---------------------------------------------------------------------------
__global__ void pool_kernel(const unsigned short* __restrict__ xb,
                            const int*   __restrict__ ecol,
                            const float* __restrict__ eval,
                            const int*   __restrict__ offs,
                            unsigned short* __restrict__ pooled) {
    const int bg     = blockIdx.x & 7;    // batch group == XCD
    const int rowblk = blockIdx.x >> 3;   // 0..3499
    const int wave = threadIdx.x >> 6;
    const int lane = threadIdx.x & 63;
    const int rsub = lane >> 5;
    const int bsub = (lane >> 4) & 1;
    const int sl   = lane & 15;

    const int r = rowblk * 8 + wave * 2 + rsub;
    const int b = bg + 8 * bsub;

    const int start = offs[r], end = offs[r + 1];

    float4 acc = make_float4(0.f, 0.f, 0.f, 0.f);
    const unsigned short* xbb = xb + (size_t)b * N_IN * C + sl * 4;

    for (int e = start; e < end; e += 4) {
        const int nn = end - e;           // >= 1
        int   cl[4]; float vv[4];
        #pragma unroll
        for (int j = 0; j < 4; ++j) {
            const int ee = (j < nn) ? e + j : e;   // clamp: valid addr, weight 0
            cl[j] = ecol[ee];
            vv[j] = (j < nn) ? eval[ee] : 0.f;
        }
        ushort4 xv[4];
        #pragma unroll
        for (int j = 0; j < 4; ++j)
            xv[j] = *(const ushort4*)(xbb + (size_t)cl[j] * C);
        #pragma unroll
        for (int j = 0; j < 4; ++j) {
            acc.x = fmaf(bf2f(xv[j].x), vv[j], acc.x);
            acc.y = fmaf(bf2f(xv[j].y), vv[j], acc.y);
            acc.z = fmaf(bf2f(xv[j].z), vv[j], acc.z);
            acc.w = fmaf(bf2f(xv[j].w), vv[j], acc.w);
        }
    }

    unsigned long long ov =
        (unsigned long long)f2bf(acc.x)
        | ((unsigned long long)f2bf(acc.y) << 16)
        | ((unsigned long long)f2bf(acc.z) << 32)
        | ((unsigned long long)f2bf(acc.w) << 48);
    unsigned short* dst = pooled + (size_t)bsub * (N_OUT * 512)
                        + (size_t)r * 512 + bg * 64 + sl * 4;
    __builtin_nontemporal_store(ov, (unsigned long long*)dst);
}

// ---------------------------------------------------------------------------
// Gathered GEMM, cross-batch-shared gathers.
// R8: break the m97 barrier-drain. R7 analysis: hipcc's __syncthreads
// emits s_waitcnt vmcnt(0) -> every stage pays (latency - compute) ~400-
// 700 cyc with the pipe EMPTIED 9x per block. Fix (T3+T4, m201 pattern):
//  - prefetch depth 2: loads for s+2 issued during stage s, held in regs
//  - raw __builtin_amdgcn_s_barrier() preceded ONLY by lgkmcnt(0)
//    (ds_write visibility); vmcnt NOT drained -> the s+2 loads stay in
//    flight across the barrier. hipcc's own counted vmcnt at each
//    ds_write waits only for the s+1 loads.
// Race discipline: apool strictly dbuf. Stage s: all waves ds_read cur
// (own-wave lgkm waits before MFMA), ds_write nxt, lgkm(0), barrier.
// Next stage writes cur only after that barrier, by which point every
// wave's reads of cur have retired. Uniform control flow (guards on s
// only) -> equal barrier count per wave.
// Block = 32 rows x 8 batches (wave = batch). Gathered row = contiguous
// 1 KB chunk pooled[g][r][*][*], one coalesced 64-lane x 16 B load,
// LDS chunk XOR-swizzle. 81,920 B LDS -> 2 blocks/CU.
// ---------------------------------------------------------------------------
#define BARRIER_NODRAIN() do {                                   \
    asm volatile("s_waitcnt lgkmcnt(0)" ::: "memory");           \
    __builtin_amdgcn_s_barrier();                                \
} while (0)

__global__ __launch_bounds__(512, 4)
void spiral_mfma(const unsigned short* __restrict__ pooled,
                 const bf16x8*         __restrict__ packedW,
                 const int*            __restrict__ sp,
                 const float*          __restrict__ bias,
                 float*                __restrict__ out) {
    const int Lb    = blockIdx.x;           // 0..1749
    const int g     = Lb & 1;               // batch group (8 batches)
    const int mtile = Lb >> 1;              // 0..874 (875*32 == 28000)
    const int tid   = threadIdx.x;
    const int wave  = tid >> 6;             // 0..7 == batch within group
    const int lane  = tid & 63;
    const int lm    = lane & 15;
    const int quad  = lane >> 4;
    const int m_base = mtile * 32;
    const int b      = g * 8 + wave;

    __shared__ unsigned short apool[2][32][512];   // 65536 B
    __shared__ bf16x8         bstage[2][512];      // 16384 B -> total 81920 B

    // Lane i (i<32) holds sp[m_base+i][s]; same content in every wave.
    int spv[S];
    {
        const int r = m_base + (lane & 31);
        #pragma unroll
        for (int s = 0; s < S; ++s) spv[s] = sp[r * S + s];
    }

    const unsigned short* pgbase = pooled + (size_t)g * (N_OUT * 512);

    f32x4 acc[2][4];
    #pragma unroll
    for (int t = 0; t < 2; ++t)
        #pragma unroll
        for (int nt = 0; nt < 4; ++nt)
            acc[t][nt] = (f32x4){0.f, 0.f, 0.f, 0.f};

    // Depth-2 staging regs: L(k) lives in set k&1.
    bf16x8 ldA2[2][4];
    bf16x8 ldB2[2];

    // Prologue: issue L(0), L(1); write L(0) -> buf 0 (compiler waits
    // vmcnt for L(0) only; L(1)'s 5 loads stay outstanding); barrier.
    #pragma unroll
    for (int q = 0; q < 4; ++q) {
        const int r = __shfl(spv[0], wave * 4 + q, 64);
        ldA2[0][q] = *(const bf16x8*)(pgbase + (size_t)r * 512 + lane * 8);
    }
    ldB2[0] = packedW[tid];
    #pragma unroll
    for (int q = 0; q < 4; ++q) {
        const int r = __shfl(spv[1], wave * 4 + q, 64);
        ldA2[1][q] = *(const bf16x8*)(pgbase + (size_t)r * 512 + lane * 8);
    }
    ldB2[1] = packedW[512 + tid];
    #pragma unroll
    for (int q = 0; q < 4; ++q) {
        const int j = wave * 4 + q;
        *(bf16x8*)(&apool[0][j][(lane ^ (j & 7)) * 8]) = ldA2[0][q];
    }
    bstage[0][tid] = ldB2[0];
    BARRIER_NODRAIN();

    #pragma unroll
    for (int s = 0; s < S; ++s) {
        const int cur = s & 1, nxt = cur ^ 1;

        // Issue L(s+2) into reg set (s&1) (freed by last stage's ds_write,
        // or by the prologue for s=0).
        if (s + 2 < S) {
            #pragma unroll
            for (int q = 0; q < 4; ++q) {
                const int r = __shfl(spv[s + 2], wave * 4 + q, 64);
                ldA2[s & 1][q] = *(const bf16x8*)(pgbase + (size_t)r * 512 + lane * 8);
            }
            ldB2[s & 1] = packedW[(s + 2) * 512 + tid];
        }

        // Compute stage s from LDS: 8 ds_reads + 16 MFMAs.
        #pragma unroll
        for (int half = 0; half < 2; ++half) {
            bf16x8 bb[4];
            #pragma unroll
            for (int nt = 0; nt < 4; ++nt)
                bb[nt] = bstage[cur][(half * 4 + nt) * 64 + lane];
            bf16x8 aa[2];
            #pragma unroll
            for (int t = 0; t < 2; ++t) {
                const int j = t * 16 + lm;
                const int chunk = wave * 8 + (((half * 4 + quad) ^ (j & 7)));
                aa[t] = *(const bf16x8*)(&apool[cur][j][chunk * 8]);
            }
            #pragma unroll
            for (int nt = 0; nt < 4; ++nt)
                #pragma unroll
                for (int t = 0; t < 2; ++t)
                    acc[t][nt] = __builtin_amdgcn_mfma_f32_16x16x32_bf16(
                        aa[t], bb[nt], acc[t][nt], 0, 0, 0);
        }

        // Write L(s+1) (reg set (s+1)&1) into buf nxt. Compiler emits a
        // counted vmcnt here (waits L(s+1), leaves L(s+2) in flight).
        if (s + 1 < S) {
            #pragma unroll
            for (int q = 0; q < 4; ++q) {
                const int j = wave * 4 + q;
                *(bf16x8*)(&apool[nxt][j][(lane ^ (j & 7)) * 8]) = ldA2[(s + 1) & 1][q];
            }
            bstage[nxt][tid] = ldB2[(s + 1) & 1];
        }
        BARRIER_NODRAIN();
    }

    // Epilogue: bias + ELU + nontemporal store (out is a pure stream).
    #pragma unroll
    for (int nt = 0; nt < 4; ++nt) {
        const int n = nt * 16 + lm;
        const float bs = bias[n];
        #pragma unroll
        for (int t = 0; t < 2; ++t) {
            #pragma unroll
            for (int reg = 0; reg < 4; ++reg) {
                const int r = m_base + t * 16 + quad * 4 + reg;
                float v = acc[t][nt][reg] + bs;
                v = v > 0.f ? v : (__expf(v) - 1.0f);
                __builtin_nontemporal_store(v,
                    out + ((size_t)b * N_OUT + r) * C + n);
            }
        }
    }
}

// ---------------------------------------------------------------------------
// Launch. Inputs: 0:x 1:values 2:weight 3:bias 4:row 5:col 6:spiral_indices
// 6 dispatches (was 8). Workspace ~73 MB.
// ---------------------------------------------------------------------------
extern "C" void kernel_launch(void* const* d_in, const int* in_sizes, int n_in,
                              void* d_out, int out_size, void* d_ws, size_t ws_size,
                              hipStream_t stream) {
    const float* x      = (const float*)d_in[0];
    const float* values = (const float*)d_in[1];
    const float* weight = (const float*)d_in[2];
    const float* bias   = (const float*)d_in[3];
    const int*   row    = (const int*)d_in[4];
    const int*   col    = (const int*)d_in[5];
    const int*   sp     = (const int*)d_in[6];
    float*       out    = (float*)d_out;

    char* ws = (char*)d_ws;
    size_t off = 0;
    unsigned short* pooled  = (unsigned short*)(ws + off); off += (size_t)B * N_OUT * C * 2;      // 57,344,000
    unsigned short* packedW = (unsigned short*)(ws + off); off += (size_t)KB * 4 * 64 * 8 * 2;    // 73,728
    unsigned short* xbf     = (unsigned short*)(ws + off); off += (size_t)B * N_IN * C * 2;       // 14,336,000
    int*   offs   = (int*)(ws + off); off += ((size_t)(N_OUT + 1) * 4 + 124) / 128 * 128;
    int*   cursor = (int*)(ws + off); off += (size_t)N_OUT * 4 + 128;
    int*   cnt    = (int*)(ws + off); off += (size_t)N_OUT * 4 + 128;
    int*   ecol   = (int*)(ws + off); off += (size_t)NNZ * 4;
    float* eval   = (float*)(ws + off); off += (size_t)NNZ * 4;

    // cnt must start at zero (ws is poisoned each call).
    (void)hipMemsetAsync(cnt, 0, (size_t)N_OUT * 4, stream);

    // Fused prep: x->bf16 + row histogram + W pack.
    prep_kernel<<<XBF_BLOCKS + HIST_BLOCKS + PACK_BLOCKS, 256, 0, stream>>>(
        x, xbf, weight, packedW, row, cnt);

    // Coalesced block scan.
    scan_kernel<<<1, 1024, 0, stream>>>(cnt, offs, cursor);

    // CSR placement.
    place_kernel<<<(NNZ + 255) / 256, 256, 0, stream>>>(row, col, values, cursor, ecol, eval);

    // Pool into bf16 [g][r][bp][c]: XCD-pinned batch pairs, bf16 gathers.
    pool_kernel<<<3500 * 8, 256, 0, stream>>>(xbf, ecol, eval, offs, pooled);

    // Gathered GEMM + bias + ELU: depth-2 prefetch, no-drain barriers.
    spiral_mfma<<<875 * 2, 512, 0, stream>>>(pooled,
        reinterpret_cast<const bf16x8*>(packedW), sp, bias, out);
}